// Round 1
// baseline (134.738 us; speedup 1.0000x reference)
//
#include <hip/hip_runtime.h>

// Problem constants (fixed by the reference):
//   x: (16, 3, 512, 512) fp32; q_param (1,10,3); all weights tiny.
//   HEAD_DIM = 1 -> SCALE = 1; heads == channels == 3.
#define B_SZ 16
#define NPIX (512 * 512)
#define NPARAM 10
#define BLOCKS_PER_BATCH 64
#define NTHREADS 256
#define PIX_PER_BLOCK (NPIX / BLOCKS_PER_BATCH)  // 4096
#define PITER (PIX_PER_BLOCK / (NTHREADS * 4))   // 4 iterations, 4 px/thread/iter

// ws layout: float[B][3][NPARAM][2] -> {sum_e, sum_ev}, 960 floats
__device__ __forceinline__ int ws_off(int b, int hd, int p) {
    return ((b * 3 + hd) * NPARAM + p) * 2;
}

// ---------------------------------------------------------------------------
// Stage 1: per-pixel LN -> k,v -> streaming softmax partial sums.
// Runtime dedupe: if q_param is uniform across params (it is: all ones),
// one pass with 6 accumulators; otherwise loop over the 10 params
// (re-reads x, which is L3-resident -> acceptable fallback).
// ---------------------------------------------------------------------------
__global__ __launch_bounds__(NTHREADS) void stage1_kernel(
    const float* __restrict__ x, const float* __restrict__ q_param,
    const float* __restrict__ ln1_w, const float* __restrict__ ln1_b,
    const float* __restrict__ Wk, const float* __restrict__ bk,
    const float* __restrict__ Wv, const float* __restrict__ bv,
    float* __restrict__ ws)
{
    const int tid = threadIdx.x;
    const int wid = tid >> 6;
    const int b = blockIdx.x / BLOCKS_PER_BATCH;
    const int chunk = blockIdx.x % BLOCKS_PER_BATCH;

    __shared__ float red[4][6];

    const float lw0 = ln1_w[0], lw1 = ln1_w[1], lw2 = ln1_w[2];
    const float lb0 = ln1_b[0], lb1 = ln1_b[1], lb2 = ln1_b[2];
    float wk[9], wv[9], bk3[3], bv3[3];
#pragma unroll
    for (int i = 0; i < 9; ++i) { wk[i] = Wk[i]; wv[i] = Wv[i]; }
#pragma unroll
    for (int i = 0; i < 3; ++i) { bk3[i] = bk[i]; bv3[i] = bv[i]; }

    // Uniform-q check (same value for every param p, per head).
    bool uniform = true;
#pragma unroll
    for (int p = 1; p < NPARAM; ++p)
#pragma unroll
        for (int hd = 0; hd < 3; ++hd)
            uniform = uniform && (q_param[p * 3 + hd] == q_param[hd]);
    const int np_eff = uniform ? 1 : NPARAM;

    const float* xb = x + (size_t)b * 3 * NPIX + (size_t)chunk * PIX_PER_BLOCK;
    const float SCALE = 1.0f;  // HEAD_DIM^-0.5 with HEAD_DIM=1

    for (int pi = 0; pi < np_eff; ++pi) {
        // Fold q*SCALE into the K projection (score = (q*s*Wk) @ h + q*s*bk).
        const float qs0 = q_param[pi * 3 + 0] * SCALE;
        const float qs1 = q_param[pi * 3 + 1] * SCALE;
        const float qs2 = q_param[pi * 3 + 2] * SCALE;
        float kw[9], kb3[3];
#pragma unroll
        for (int j = 0; j < 3; ++j) {
            kw[0 * 3 + j] = wk[0 * 3 + j] * qs0;
            kw[1 * 3 + j] = wk[1 * 3 + j] * qs1;
            kw[2 * 3 + j] = wk[2 * 3 + j] * qs2;
        }
        kb3[0] = bk3[0] * qs0; kb3[1] = bk3[1] * qs1; kb3[2] = bk3[2] * qs2;

        float ae0 = 0.f, ae1 = 0.f, ae2 = 0.f;
        float av0 = 0.f, av1 = 0.f, av2 = 0.f;

        for (int it = 0; it < PITER; ++it) {
            const int n = it * (NTHREADS * 4) + tid * 4;
            const float4 xr = *(const float4*)(xb + 0 * NPIX + n);
            const float4 xg = *(const float4*)(xb + 1 * NPIX + n);
            const float4 xl = *(const float4*)(xb + 2 * NPIX + n);
            const float rr[4] = {xr.x, xr.y, xr.z, xr.w};
            const float gg[4] = {xg.x, xg.y, xg.z, xg.w};
            const float ll[4] = {xl.x, xl.y, xl.z, xl.w};
#pragma unroll
            for (int j = 0; j < 4; ++j) {
                const float a0 = rr[j], a1 = gg[j], a2 = ll[j];
                // LayerNorm over 3 channels
                const float m = (a0 + a1 + a2) * (1.0f / 3.0f);
                const float d0 = a0 - m, d1 = a1 - m, d2 = a2 - m;
                const float var = (d0 * d0 + d1 * d1 + d2 * d2) * (1.0f / 3.0f);
                const float ri = rsqrtf(var + 1e-5f);
                const float h0 = d0 * ri * lw0 + lb0;
                const float h1 = d1 * ri * lw1 + lb1;
                const float h2 = d2 * ri * lw2 + lb2;
                // scores (q folded in) and v
                const float s0 = kw[0] * h0 + kw[1] * h1 + kw[2] * h2 + kb3[0];
                const float s1 = kw[3] * h0 + kw[4] * h1 + kw[5] * h2 + kb3[1];
                const float s2 = kw[6] * h0 + kw[7] * h1 + kw[8] * h2 + kb3[2];
                const float v0 = wv[0] * h0 + wv[1] * h1 + wv[2] * h2 + bv3[0];
                const float v1 = wv[3] * h0 + wv[4] * h1 + wv[5] * h2 + bv3[1];
                const float v2 = wv[6] * h0 + wv[7] * h1 + wv[8] * h2 + bv3[2];
                // Scores are bounded (|h|<=sqrt(3), |Wk|~0.06) -> no max-sub needed.
                const float e0 = __expf(s0);
                const float e1 = __expf(s1);
                const float e2 = __expf(s2);
                ae0 += e0; ae1 += e1; ae2 += e2;
                av0 += e0 * v0; av1 += e1 * v1; av2 += e2 * v2;
            }
        }

        // Block reduction of 6 values, then 1 atomic per value per block.
        float vals[6] = {ae0, av0, ae1, av1, ae2, av2};
#pragma unroll
        for (int i = 0; i < 6; ++i) {
            float v = vals[i];
#pragma unroll
            for (int off = 32; off > 0; off >>= 1) v += __shfl_xor(v, off, 64);
            if ((tid & 63) == 0) red[wid][i] = v;
        }
        __syncthreads();
        if (tid < 6) {
            const float s = red[0][tid] + red[1][tid] + red[2][tid] + red[3][tid];
            const int hd = tid >> 1, which = tid & 1;
            atomicAdd(ws + ws_off(b, hd, pi) + which, s);
        }
        __syncthreads();
    }
}

// ---------------------------------------------------------------------------
// Stage 2: tiny epilogue. 160 threads, one per (b, p):
// o = attn@v -> @Wp.T+bp -> LN2 -> FFN(silu) -> residual -> gamma/color heads.
// ---------------------------------------------------------------------------
__global__ __launch_bounds__(192) void stage2_kernel(
    const float* __restrict__ q_param,
    const float* __restrict__ Wp, const float* __restrict__ bp,
    const float* __restrict__ ln2_w, const float* __restrict__ ln2_b,
    const float* __restrict__ W1, const float* __restrict__ b1,
    const float* __restrict__ W2, const float* __restrict__ b2,
    const float* __restrict__ Wg, const float* __restrict__ bg,
    const float* __restrict__ Wc, const float* __restrict__ bc,
    const float* __restrict__ gamma_base, const float* __restrict__ color_base,
    const float* __restrict__ ws, float* __restrict__ out)
{
    const int t = threadIdx.x;
    if (t >= B_SZ * NPARAM) return;
    const int b = t / NPARAM, p = t % NPARAM;

    bool uniform = true;
#pragma unroll
    for (int p2 = 1; p2 < NPARAM; ++p2)
#pragma unroll
        for (int hd = 0; hd < 3; ++hd)
            uniform = uniform && (q_param[p2 * 3 + hd] == q_param[hd]);
    const int sp = uniform ? 0 : p;

    float o[3];
#pragma unroll
    for (int hd = 0; hd < 3; ++hd) {
        const float se = ws[ws_off(b, hd, sp)];
        const float sv = ws[ws_off(b, hd, sp) + 1];
        o[hd] = sv / se;
    }
    // o @ Wp.T + bp
    float o2[3];
#pragma unroll
    for (int i = 0; i < 3; ++i)
        o2[i] = Wp[i * 3 + 0] * o[0] + Wp[i * 3 + 1] * o[1] + Wp[i * 3 + 2] * o[2] + bp[i];
    // LN2
    const float m = (o2[0] + o2[1] + o2[2]) * (1.0f / 3.0f);
    const float d0 = o2[0] - m, d1 = o2[1] - m, d2 = o2[2] - m;
    const float var = (d0 * d0 + d1 * d1 + d2 * d2) * (1.0f / 3.0f);
    const float ri = rsqrtf(var + 1e-5f);
    const float h0 = d0 * ri * ln2_w[0] + ln2_b[0];
    const float h1 = d1 * ri * ln2_w[1] + ln2_b[1];
    const float h2 = d2 * ri * ln2_w[2] + ln2_b[2];
    // FFN: silu(h @ W1.T + b1) @ W2.T + b2
    float f0 = b2[0], f1 = b2[1], f2 = b2[2];
#pragma unroll
    for (int kk = 0; kk < 12; ++kk) {
        const float z = W1[kk * 3 + 0] * h0 + W1[kk * 3 + 1] * h1 + W1[kk * 3 + 2] * h2 + b1[kk];
        const float s = z / (1.0f + __expf(-z));  // silu
        f0 += W2[0 * 12 + kk] * s;
        f1 += W2[1 * 12 + kk] * s;
        f2 += W2[2 * 12 + kk] * s;
    }
    const float y0 = o2[0] + f0, y1 = o2[1] + f1, y2 = o2[2] + f2;

    if (p == 0) {
        out[b] = y0 * Wg[0] + y1 * Wg[1] + y2 * Wg[2] + bg[0] + gamma_base[0];
    } else {
        const int idx = p - 1;
        out[B_SZ + b * 9 + idx] =
            y0 * Wc[0] + y1 * Wc[1] + y2 * Wc[2] + bc[0] + color_base[idx];
    }
}

extern "C" void kernel_launch(void* const* d_in, const int* in_sizes, int n_in,
                              void* d_out, int out_size, void* d_ws, size_t ws_size,
                              hipStream_t stream)
{
    const float* x          = (const float*)d_in[0];
    const float* q_param    = (const float*)d_in[1];
    const float* ln1_w      = (const float*)d_in[2];
    const float* ln1_b      = (const float*)d_in[3];
    const float* Wk         = (const float*)d_in[4];
    const float* bk         = (const float*)d_in[5];
    const float* Wv         = (const float*)d_in[6];
    const float* bv         = (const float*)d_in[7];
    const float* Wp         = (const float*)d_in[8];
    const float* bp         = (const float*)d_in[9];
    const float* ln2_w      = (const float*)d_in[10];
    const float* ln2_b      = (const float*)d_in[11];
    const float* W1         = (const float*)d_in[12];
    const float* b1         = (const float*)d_in[13];
    const float* W2         = (const float*)d_in[14];
    const float* b2         = (const float*)d_in[15];
    const float* Wg         = (const float*)d_in[16];
    const float* bg         = (const float*)d_in[17];
    const float* Wc         = (const float*)d_in[18];
    const float* bc         = (const float*)d_in[19];
    const float* gamma_base = (const float*)d_in[20];
    const float* color_base = (const float*)d_in[21];

    float* ws = (float*)d_ws;
    float* out = (float*)d_out;

    // ws accumulators must start at zero (harness poisons d_ws with 0xAA).
    hipMemsetAsync(ws, 0, B_SZ * 3 * NPARAM * 2 * sizeof(float), stream);

    stage1_kernel<<<B_SZ * BLOCKS_PER_BATCH, NTHREADS, 0, stream>>>(
        x, q_param, ln1_w, ln1_b, Wk, bk, Wv, bv, ws);
    stage2_kernel<<<1, 192, 0, stream>>>(
        q_param, Wp, bp, ln2_w, ln2_b, W1, b1, W2, b2,
        Wg, bg, Wc, bc, gamma_base, color_base, ws, out);
}